// Round 1
// baseline (239.918 us; speedup 1.0000x reference)
//
#include <hip/hip_runtime.h>
#include <math.h>

// out[tok, d] = cos(dot(x[tok,:], W1) + b1) * cos(phi) * W2[d] + b2[d]
// D = 1024. Problem shape is FIXED by the reference: B=8, S=4096 -> 32768 tokens.
//
// NOTE: previous version derived ntok = in_sizes[0] / EMBED_D. If in_sizes is in
// BYTES that launches 131072 blocks (4x the work, OOB reads/writes absorbed by the
// workspace) — consistent with the measured 230us being exactly 4x the ~57us
// roofline. Shape is fixed by the problem, so we hardcode NTOK.
//
// Structure: one WAVE (64 lanes) per token, no __syncthreads at all.
//  - lane l owns float4 chunks {c*64+l : c=0..3} of the 1024-wide row
//  - W1/W2/b2 cached in registers once per wave (they're reused for every token)
//  - dot-product partial reduced with a 6-step __shfl_xor butterfly: every lane
//    ends up holding the full sum, so no LDS, no broadcast, no barrier
//  - grid-stride loop: 2048 long-lived blocks (8192 waves), ~4 tokens/wave

#define EMBED_D 1024
#define NTOK    (8 * 4096)

__global__ __launch_bounds__(256) void ffq_kernel(
    const float* __restrict__ x,
    const float* __restrict__ W1,
    const float* __restrict__ b1,
    const float* __restrict__ phi,
    const float* __restrict__ W2,
    const float* __restrict__ b2,
    float* __restrict__ out,
    int ntok)
{
    const int lane  = threadIdx.x & 63;
    const int wib   = threadIdx.x >> 6;            // wave index in block: 0..3
    const int gwave = blockIdx.x * 4 + wib;        // global wave id
    const int nwav  = gridDim.x * 4;

    // Per-wave register cache of the broadcast operands (4 KiB each, reused
    // for every token this wave processes).
    float4 w1r[4], w2r[4], b2r[4];
    const float4* w14 = (const float4*)W1;
    const float4* w24 = (const float4*)W2;
    const float4* b24 = (const float4*)b2;
    #pragma unroll
    for (int c = 0; c < 4; ++c) {
        w1r[c] = w14[c * 64 + lane];
        w2r[c] = w24[c * 64 + lane];
        b2r[c] = b24[c * 64 + lane];
    }
    const float cphi = cosf(phi[0]);
    const float b1v  = b1[0];

    for (int tok = gwave; tok < ntok; tok += nwav) {
        const float4* x4 = (const float4*)(x + (size_t)tok * EMBED_D);

        // 4 coalesced 1 KiB wave-loads cover the 4 KiB row; issue all before use.
        float4 xv[4];
        #pragma unroll
        for (int c = 0; c < 4; ++c) xv[c] = x4[c * 64 + lane];

        float v = 0.f;
        #pragma unroll
        for (int c = 0; c < 4; ++c) {
            v = fmaf(xv[c].x, w1r[c].x, v);
            v = fmaf(xv[c].y, w1r[c].y, v);
            v = fmaf(xv[c].z, w1r[c].z, v);
            v = fmaf(xv[c].w, w1r[c].w, v);
        }

        // Butterfly reduce across the 64-lane wave: all lanes hold the sum.
        #pragma unroll
        for (int m = 32; m > 0; m >>= 1)
            v += __shfl_xor(v, m, 64);

        // Every lane computes q redundantly (VALU is idle anyway; avoids any
        // serial single-lane section + broadcast).
        const float q = cosf(v + b1v) * cphi;

        float4* o4 = (float4*)(out + (size_t)tok * EMBED_D);
        #pragma unroll
        for (int c = 0; c < 4; ++c) {
            float4 o;
            o.x = fmaf(q, w2r[c].x, b2r[c].x);
            o.y = fmaf(q, w2r[c].y, b2r[c].y);
            o.z = fmaf(q, w2r[c].z, b2r[c].z);
            o.w = fmaf(q, w2r[c].w, b2r[c].w);
            o4[c * 64 + lane] = o;
        }
    }
}

extern "C" void kernel_launch(void* const* d_in, const int* in_sizes, int n_in,
                              void* d_out, int out_size, void* d_ws, size_t ws_size,
                              hipStream_t stream) {
    const float* x   = (const float*)d_in[0];
    const float* W1  = (const float*)d_in[1];
    const float* b1  = (const float*)d_in[2];
    const float* phi = (const float*)d_in[3];
    const float* W2  = (const float*)d_in[4];
    const float* b2  = (const float*)d_in[5];
    float* out = (float*)d_out;

    // Fixed problem shape (see header comment): do NOT derive from in_sizes,
    // whose units (bytes vs elements) are ambiguous and previously caused a
    // 4x-oversized grid under the bytes interpretation.
    const int ntok = NTOK;

    // 2048 blocks x 4 waves = 8192 waves, grid-stride over 32768 tokens.
    ffq_kernel<<<2048, 256, 0, stream>>>(x, W1, b1, phi, W2, b2, out, ntok);
}